// Round 5
// baseline (683.377 us; speedup 1.0000x reference)
//
#include <hip/hip_runtime.h>
#include <math.h>

// Problem constants (fixed by reference)
#define NF 8
#define NK 16
#define BB 32
#define YY 32
#define XX 32
#define PP 16
#define TT 8
#define YX (YY*XX)     // 1024
#define PT (PP*TT)     // 128
#define YXPT (YX*PT)   // 131072
#define CHUNKS 8
#define COLS_PER_BLOCK (YX/CHUNKS)        // 128
#define COLS_PER_WAVE  (COLS_PER_BLOCK/4) // 32
#define MAIN_ITERS     (COLS_PER_WAVE/2)  // 16 (2 columns per wave-iter)

// Workspace layout (float offsets)
#define WPT_OFF   0                          // [NF][NK][PT]         = 16384
#define WYX_OFF   (NF*NK*PT)                 // [NF][YX][NK]         = 131072
#define QMEAN_OFF (WYX_OFF + NF*YX*NK)       // [YXPT]               = 131072
#define ACC_OFF   (QMEAN_OFF + YXPT)         // [CHUNKS][BB*NF*NK]   = 32768
#define INTG_OFF  (ACC_OFF + CHUNKS*BB*NF*NK)// [4][NF*NK]           = 512

// ---------------------------------------------------------------------------
// K1: blocks 0..511  -> qmean (b-split 4 ways + LDS reduce)
//     blocks 512..639-> weight tables, one block per (f,k)
// ---------------------------------------------------------------------------
__global__ __launch_bounds__(256) void k_prep(const float* __restrict__ quad,
                       const float* __restrict__ mean_lat, const float* __restrict__ logstd_lat,
                       const float* __restrict__ mean_lon, const float* __restrict__ logstd_lon,
                       const float* __restrict__ mean_lev, const float* __restrict__ logstd_lev,
                       const float* __restrict__ logtau,
                       float* __restrict__ ws) {
    const int tid = threadIdx.x, bx = blockIdx.x;

    if (bx < 512) {
        __shared__ float4 sm[256];
        const int j4 = bx * 64 + (tid & 63);
        const int bg = tid >> 6;
        const float4* q4 = (const float4*)quad;
        float4 a = make_float4(0.f, 0.f, 0.f, 0.f);
        #pragma unroll
        for (int i = 0; i < 8; ++i) {
            float4 v = q4[(size_t)(bg * 8 + i) * (YXPT / 4) + j4];
            a.x += v.x; a.y += v.y; a.z += v.z; a.w += v.w;
        }
        sm[tid] = a;
        __syncthreads();
        if (tid < 64) {
            float4 r0 = sm[tid], r1 = sm[tid + 64], r2 = sm[tid + 128], r3 = sm[tid + 192];
            float4 r;
            r.x = (r0.x + r1.x + r2.x + r3.x) * (1.f / BB);
            r.y = (r0.y + r1.y + r2.y + r3.y) * (1.f / BB);
            r.z = (r0.z + r1.z + r2.z + r3.z) * (1.f / BB);
            r.w = (r0.w + r1.w + r2.w + r3.w) * (1.f / BB);
            ((float4*)(ws + QMEAN_OFF))[j4] = r;
        }
        return;
    }
    // weight tables: one block per fk, 128 active threads
    const int fk = bx - 512;
    if (tid >= 128) return;
    const int f = fk >> 4, k = fk & 15;
    const float mlat = mean_lat[fk], slat = expf(logstd_lat[fk]);
    const float mlon = mean_lon[fk], slon = expf(logstd_lon[fk]);
    const float mlev = mean_lev[fk], slev = expf(logstd_lev[fk]);
    const float tau  = expf(logtau[fk]) + 1e-4f;

    {   // wpt[fk][tid]:  p = tid>>3, t = tid&7  (coalesced store)
        const int p = tid >> 3, t = tid & 7;
        const float cp = -1.f + 2.f * (float)p / (PP - 1);
        const float zp = (cp - mlev) / slev;
        ws[WPT_OFF + fk * PT + tid] = expf(-0.5f * zp * zp) * expf(-(float)t / tau);
    }
    #pragma unroll
    for (int i = 0; i < 8; ++i) {   // wyx[f][yx][k]
        const int yx = i * 128 + tid;
        const int y = yx >> 5, x = yx & 31;
        const float cy = -1.f + 2.f * (float)y / (YY - 1);
        const float cx = -1.f + 2.f * (float)x / (XX - 1);
        const float zy = (cy - mlat) / slat;
        const float zx = (cx - mlon) / slon;
        ws[WYX_OFF + (f * YX + yx) * NK + k] = expf(-0.5f * zy * zy) * expf(-0.5f * zx * zx);
    }
}

// ---------------------------------------------------------------------------
// K2: quarter-partials of integral[f,k]; block = (fk, quarter), no atomics
// ---------------------------------------------------------------------------
__global__ __launch_bounds__(256) void k_integral(float* __restrict__ ws) {
    const int fk = blockIdx.x >> 2, qr = blockIdx.x & 3;
    const int tid = threadIdx.x;
    const int f = fk >> 4, k = fk & 15;
    const int yx = qr * 256 + tid;
    const float4* w4 = (const float4*)(ws + WPT_OFF + fk * PT);
    const float4* q4 = (const float4*)(ws + QMEAN_OFF + (size_t)yx * PT);
    float s = 0.f;
    #pragma unroll
    for (int j = 0; j < PT / 4; ++j) {
        float4 w = w4[j], q = q4[j];
        s += w.x * q.x + w.y * q.y + w.z * q.z + w.w * q.w;
    }
    float partial = ws[WYX_OFF + (f * YX + yx) * NK + k] * s;
    #pragma unroll
    for (int m = 32; m; m >>= 1) partial += __shfl_xor(partial, m);
    __shared__ float red[4];
    if ((tid & 63) == 0) red[tid >> 6] = partial;
    __syncthreads();
    if (tid == 0)
        ws[INTG_OFF + qr * (NF * NK) + fk] = red[0] + red[1] + red[2] + red[3];
}

// ---------------------------------------------------------------------------
// K3: main contraction. Block = (b, f, chunk of 128 cols); 4 waves.
// wyx slice staged in LDS (8 KB); streaming field/quad float4 loads in a
// distance-2 software pipeline (4 outstanding 16B loads/lane). Plain loads
// only — gfx950 nontemporal bypasses L2 request-merging (8x over-fetch, R4).
// Each block writes its own partial slot (no atomics, no zero-init needed).
// ---------------------------------------------------------------------------
__global__ __launch_bounds__(256, 4) void k_main(const float* __restrict__ field,
                                                 const float* __restrict__ quad,
                                                 float* __restrict__ ws) {
    const int bx = blockIdx.x;
    const int f = bx & 7, chunk = (bx >> 3) & 7, b = bx >> 6;
    const int tid = threadIdx.x;
    const int wave = tid >> 6, L = tid & 63;
    const int half = L >> 5, qg = L & 31;

    __shared__ float sw[COLS_PER_BLOCK * NK]; // 8 KB: [col][k]
    {
        const float4* src = (const float4*)(ws + WYX_OFF + (size_t)(f * YX + chunk * COLS_PER_BLOCK) * NK);
        float4* dst = (float4*)sw;
        dst[tid] = src[tid];
        dst[tid + 256] = src[tid + 256];
    }

    float4 wf[NK];
    #pragma unroll
    for (int k = 0; k < NK; ++k)
        wf[k] = *(const float4*)(ws + WPT_OFF + (f * NK + k) * PT + 4 * qg);

    float acc[NK];
    #pragma unroll
    for (int k = 0; k < NK; ++k) acc[k] = 0.f;

    const int colBase = chunk * COLS_PER_BLOCK + wave * COLS_PER_WAVE;
    const float4* fp = (const float4*)(field + (size_t)(b * NF + f) * YXPT + (size_t)colBase * PT + 4 * L);
    const float4* qp = (const float4*)(quad + (size_t)b * YXPT + (size_t)colBase * PT + 4 * L);
    // stride between iters: 2 columns = 256 floats = 64 float4
    const int STEP = (2 * PT) / 4;

    __syncthreads();
    const float* swc = sw + (wave * COLS_PER_WAVE + half) * NK;

    // pipeline preamble (distance 2)
    float4 fa = fp[0];
    float4 qa = qp[0];
    float4 fb = fp[STEP];
    float4 qb = qp[STEP];
    float4 ga;
    ga.x = fa.x * qa.x; ga.y = fa.y * qa.y; ga.z = fa.z * qa.z; ga.w = fa.w * qa.w;

    #pragma unroll
    for (int s = 0; s < MAIN_ITERS; ++s) {
        float4 fc = fb, qc = qb;
        if (s + 2 < MAIN_ITERS) {
            fc = fp[(s + 2) * STEP];
            qc = qp[(s + 2) * STEP];
        }
        const float4* wvp = (const float4*)(swc + s * 2 * NK);
        #pragma unroll
        for (int j = 0; j < 4; ++j) {
            float4 w = wvp[j];
            {
                const int k = 4 * j;
                float d = ga.x * wf[k].x;
                d = fmaf(ga.y, wf[k].y, d);
                d = fmaf(ga.z, wf[k].z, d);
                d = fmaf(ga.w, wf[k].w, d);
                acc[k] = fmaf(w.x, d, acc[k]);
            }
            {
                const int k = 4 * j + 1;
                float d = ga.x * wf[k].x;
                d = fmaf(ga.y, wf[k].y, d);
                d = fmaf(ga.z, wf[k].z, d);
                d = fmaf(ga.w, wf[k].w, d);
                acc[k] = fmaf(w.y, d, acc[k]);
            }
            {
                const int k = 4 * j + 2;
                float d = ga.x * wf[k].x;
                d = fmaf(ga.y, wf[k].y, d);
                d = fmaf(ga.z, wf[k].z, d);
                d = fmaf(ga.w, wf[k].w, d);
                acc[k] = fmaf(w.z, d, acc[k]);
            }
            {
                const int k = 4 * j + 3;
                float d = ga.x * wf[k].x;
                d = fmaf(ga.y, wf[k].y, d);
                d = fmaf(ga.z, wf[k].z, d);
                d = fmaf(ga.w, wf[k].w, d);
                acc[k] = fmaf(w.w, d, acc[k]);
            }
        }
        if (s + 1 < MAIN_ITERS) {
            ga.x = fb.x * qb.x; ga.y = fb.y * qb.y; ga.z = fb.z * qb.z; ga.w = fb.w * qb.w;
            fb = fc; qb = qc;
        }
    }

    // wave butterfly -> cross-wave LDS -> one plain store per k (chunk slot)
    __shared__ float red[4][NK];
    #pragma unroll
    for (int k = 0; k < NK; ++k) {
        float v = acc[k];
        v += __shfl_xor(v, 32); v += __shfl_xor(v, 16); v += __shfl_xor(v, 8);
        v += __shfl_xor(v, 4);  v += __shfl_xor(v, 2);  v += __shfl_xor(v, 1);
        if (L == 0) red[wave][k] = v;
    }
    __syncthreads();
    if (tid < NK) {
        float s2 = red[0][tid] + red[1][tid] + red[2][tid] + red[3][tid];
        ws[ACC_OFF + chunk * (BB * NF * NK) + (b * NF + f) * NK + tid] = s2;
    }
}

// ---------------------------------------------------------------------------
// K4: out[b,f,k] = sum_c accP[c] / (1e-4 + sum_q intgP[q])
// ---------------------------------------------------------------------------
__global__ void k_final(const float* __restrict__ ws, float* __restrict__ out) {
    int i = blockIdx.x * 256 + threadIdx.x;
    if (i >= BB * NF * NK) return;
    float a = 0.f;
    #pragma unroll
    for (int c = 0; c < CHUNKS; ++c) a += ws[ACC_OFF + c * (BB * NF * NK) + i];
    const int fk = i & (NF * NK - 1);
    float g = 1e-4f;
    #pragma unroll
    for (int q = 0; q < 4; ++q) g += ws[INTG_OFF + q * (NF * NK) + fk];
    out[i] = a / g;
}

extern "C" void kernel_launch(void* const* d_in, const int* in_sizes, int n_in,
                              void* d_out, int out_size, void* d_ws, size_t ws_size,
                              hipStream_t stream) {
    const float* field = (const float*)d_in[0];
    const float* quad  = (const float*)d_in[1];
    float* ws = (float*)d_ws;

    k_prep<<<640, 256, 0, stream>>>(quad,
        (const float*)d_in[2], (const float*)d_in[3],
        (const float*)d_in[4], (const float*)d_in[5],
        (const float*)d_in[6], (const float*)d_in[7],
        (const float*)d_in[8], ws);
    k_integral<<<NF * NK * 4, 256, 0, stream>>>(ws);
    k_main<<<BB * NF * CHUNKS, 256, 0, stream>>>(field, quad, ws);
    k_final<<<(BB * NF * NK + 255) / 256, 256, 0, stream>>>(ws, (float*)d_out);
}

// Round 6
// 240.169 us; speedup vs baseline: 2.8454x; 2.8454x over previous
//
#include <hip/hip_runtime.h>
#include <math.h>

// Problem constants (fixed by reference)
#define NF 8
#define NK 16
#define BB 32
#define YY 32
#define XX 32
#define PP 16
#define TT 8
#define YX (YY*XX)     // 1024
#define PT (PP*TT)     // 128
#define YXPT (YX*PT)   // 131072
#define CHUNKS 8
#define COLS_PER_BLOCK (YX/CHUNKS)        // 128
#define COLS_PER_WAVE  (COLS_PER_BLOCK/4) // 32
#define MAIN_ITERS     (COLS_PER_WAVE/2)  // 16 (2 columns per wave-iter)

// Workspace layout (float offsets)
#define WPT_OFF   0                          // [NF][NK][PT]         = 16384
#define WYX_OFF   (NF*NK*PT)                 // [NF][YX][NK]         = 131072
#define QMEAN_OFF (WYX_OFF + NF*YX*NK)       // [YXPT]               = 131072
#define ACC_OFF   (QMEAN_OFF + YXPT)         // [CHUNKS][BB*NF*NK]   = 32768
#define INTG_OFF  (ACC_OFF + CHUNKS*BB*NF*NK)// [4][NF*NK]           = 512

// ---------------------------------------------------------------------------
// K1: blocks 0..511  -> qmean (b-split 4 ways + LDS reduce)
//     blocks 512..639-> weight tables, one block per (f,k)
// ---------------------------------------------------------------------------
__global__ __launch_bounds__(256) void k_prep(const float* __restrict__ quad,
                       const float* __restrict__ mean_lat, const float* __restrict__ logstd_lat,
                       const float* __restrict__ mean_lon, const float* __restrict__ logstd_lon,
                       const float* __restrict__ mean_lev, const float* __restrict__ logstd_lev,
                       const float* __restrict__ logtau,
                       float* __restrict__ ws) {
    const int tid = threadIdx.x, bx = blockIdx.x;

    if (bx < 512) {
        __shared__ float4 sm[256];
        const int j4 = bx * 64 + (tid & 63);
        const int bg = tid >> 6;
        const float4* q4 = (const float4*)quad;
        float4 a = make_float4(0.f, 0.f, 0.f, 0.f);
        #pragma unroll
        for (int i = 0; i < 8; ++i) {
            float4 v = q4[(size_t)(bg * 8 + i) * (YXPT / 4) + j4];
            a.x += v.x; a.y += v.y; a.z += v.z; a.w += v.w;
        }
        sm[tid] = a;
        __syncthreads();
        if (tid < 64) {
            float4 r0 = sm[tid], r1 = sm[tid + 64], r2 = sm[tid + 128], r3 = sm[tid + 192];
            float4 r;
            r.x = (r0.x + r1.x + r2.x + r3.x) * (1.f / BB);
            r.y = (r0.y + r1.y + r2.y + r3.y) * (1.f / BB);
            r.z = (r0.z + r1.z + r2.z + r3.z) * (1.f / BB);
            r.w = (r0.w + r1.w + r2.w + r3.w) * (1.f / BB);
            ((float4*)(ws + QMEAN_OFF))[j4] = r;
        }
        return;
    }
    // weight tables: one block per fk, 128 active threads
    const int fk = bx - 512;
    if (tid >= 128) return;
    const int f = fk >> 4, k = fk & 15;
    const float mlat = mean_lat[fk], slat = expf(logstd_lat[fk]);
    const float mlon = mean_lon[fk], slon = expf(logstd_lon[fk]);
    const float mlev = mean_lev[fk], slev = expf(logstd_lev[fk]);
    const float tau  = expf(logtau[fk]) + 1e-4f;

    {   // wpt[fk][tid]:  p = tid>>3, t = tid&7  (coalesced store)
        const int p = tid >> 3, t = tid & 7;
        const float cp = -1.f + 2.f * (float)p / (PP - 1);
        const float zp = (cp - mlev) / slev;
        ws[WPT_OFF + fk * PT + tid] = expf(-0.5f * zp * zp) * expf(-(float)t / tau);
    }
    #pragma unroll
    for (int i = 0; i < 8; ++i) {   // wyx[f][yx][k]
        const int yx = i * 128 + tid;
        const int y = yx >> 5, x = yx & 31;
        const float cy = -1.f + 2.f * (float)y / (YY - 1);
        const float cx = -1.f + 2.f * (float)x / (XX - 1);
        const float zy = (cy - mlat) / slat;
        const float zx = (cx - mlon) / slon;
        ws[WYX_OFF + (f * YX + yx) * NK + k] = expf(-0.5f * zy * zy) * expf(-0.5f * zx * zx);
    }
}

// ---------------------------------------------------------------------------
// K2: quarter-partials of integral[f,k]; block = (fk, quarter), no atomics
// ---------------------------------------------------------------------------
__global__ __launch_bounds__(256) void k_integral(float* __restrict__ ws) {
    const int fk = blockIdx.x >> 2, qr = blockIdx.x & 3;
    const int tid = threadIdx.x;
    const int f = fk >> 4, k = fk & 15;
    const int yx = qr * 256 + tid;
    const float4* w4 = (const float4*)(ws + WPT_OFF + fk * PT);
    const float4* q4 = (const float4*)(ws + QMEAN_OFF + (size_t)yx * PT);
    float s = 0.f;
    #pragma unroll
    for (int j = 0; j < PT / 4; ++j) {
        float4 w = w4[j], q = q4[j];
        s += w.x * q.x + w.y * q.y + w.z * q.z + w.w * q.w;
    }
    float partial = ws[WYX_OFF + (f * YX + yx) * NK + k] * s;
    #pragma unroll
    for (int m = 32; m; m >>= 1) partial += __shfl_xor(partial, m);
    __shared__ float red[4];
    if ((tid & 63) == 0) red[tid >> 6] = partial;
    __syncthreads();
    if (tid == 0)
        ws[INTG_OFF + qr * (NF * NK) + fk] = red[0] + red[1] + red[2] + red[3];
}

// ---------------------------------------------------------------------------
// K3: main contraction. Block = (b, f, chunk of 128 cols); 4 waves.
// wyx slice staged in LDS (8 KB). Distance-2 software pipeline with
// #pragma unroll 1 on the outer loop: exactly 4 outstanding 16B loads/lane,
// bounded registers (~106) -- R5's full unroll hoisted ALL iteration loads
// and spilled to scratch (614 MB of spill writes). Plain loads only.
// ---------------------------------------------------------------------------
__global__ __launch_bounds__(256, 4) void k_main(const float* __restrict__ field,
                                                 const float* __restrict__ quad,
                                                 float* __restrict__ ws) {
    const int bx = blockIdx.x;
    const int f = bx & 7, chunk = (bx >> 3) & 7, b = bx >> 6;
    const int tid = threadIdx.x;
    const int wave = tid >> 6, L = tid & 63;
    const int half = L >> 5, qg = L & 31;

    __shared__ float sw[COLS_PER_BLOCK * NK]; // 8 KB: [col][k]
    {
        const float4* src = (const float4*)(ws + WYX_OFF + (size_t)(f * YX + chunk * COLS_PER_BLOCK) * NK);
        float4* dst = (float4*)sw;
        dst[tid] = src[tid];
        dst[tid + 256] = src[tid + 256];
    }

    float4 wf[NK];
    #pragma unroll
    for (int k = 0; k < NK; ++k)
        wf[k] = *(const float4*)(ws + WPT_OFF + (f * NK + k) * PT + 4 * qg);

    float acc[NK];
    #pragma unroll
    for (int k = 0; k < NK; ++k) acc[k] = 0.f;

    const int colBase = chunk * COLS_PER_BLOCK + wave * COLS_PER_WAVE;
    const float4* fp = (const float4*)(field + (size_t)(b * NF + f) * YXPT + (size_t)colBase * PT + 4 * L);
    const float4* qp = (const float4*)(quad + (size_t)b * YXPT + (size_t)colBase * PT + 4 * L);
    const int STEP = (2 * PT) / 4;   // 2 columns per iter

    __syncthreads();
    const float* swc = sw + (wave * COLS_PER_WAVE + half) * NK;

    // distance-2 pipeline preamble
    float4 fa = fp[0];
    float4 qa = qp[0];
    float4 fb = fp[STEP];
    float4 qb = qp[STEP];

    #pragma unroll 1
    for (int s = 0; s < MAIN_ITERS; ++s) {
        // prefetch s+2 (clamped, branchless; redundant tail loads are L2 hits)
        const int sn = (s + 2 < MAIN_ITERS) ? (s + 2) : 0;
        float4 fc = fp[sn * STEP];
        float4 qc = qp[sn * STEP];

        float4 ga;
        ga.x = fa.x * qa.x; ga.y = fa.y * qa.y; ga.z = fa.z * qa.z; ga.w = fa.w * qa.w;

        const float4* wvp = (const float4*)(swc + s * 2 * NK);
        #pragma unroll
        for (int j = 0; j < 4; ++j) {
            float4 w = wvp[j];
            {
                const int k = 4 * j;
                float d = ga.x * wf[k].x;
                d = fmaf(ga.y, wf[k].y, d);
                d = fmaf(ga.z, wf[k].z, d);
                d = fmaf(ga.w, wf[k].w, d);
                acc[k] = fmaf(w.x, d, acc[k]);
            }
            {
                const int k = 4 * j + 1;
                float d = ga.x * wf[k].x;
                d = fmaf(ga.y, wf[k].y, d);
                d = fmaf(ga.z, wf[k].z, d);
                d = fmaf(ga.w, wf[k].w, d);
                acc[k] = fmaf(w.y, d, acc[k]);
            }
            {
                const int k = 4 * j + 2;
                float d = ga.x * wf[k].x;
                d = fmaf(ga.y, wf[k].y, d);
                d = fmaf(ga.z, wf[k].z, d);
                d = fmaf(ga.w, wf[k].w, d);
                acc[k] = fmaf(w.z, d, acc[k]);
            }
            {
                const int k = 4 * j + 3;
                float d = ga.x * wf[k].x;
                d = fmaf(ga.y, wf[k].y, d);
                d = fmaf(ga.z, wf[k].z, d);
                d = fmaf(ga.w, wf[k].w, d);
                acc[k] = fmaf(w.w, d, acc[k]);
            }
        }
        fa = fb; qa = qb;
        fb = fc; qb = qc;
    }

    // wave butterfly -> cross-wave LDS -> one plain store per k (chunk slot)
    __shared__ float red[4][NK];
    #pragma unroll
    for (int k = 0; k < NK; ++k) {
        float v = acc[k];
        v += __shfl_xor(v, 32); v += __shfl_xor(v, 16); v += __shfl_xor(v, 8);
        v += __shfl_xor(v, 4);  v += __shfl_xor(v, 2);  v += __shfl_xor(v, 1);
        if (L == 0) red[wave][k] = v;
    }
    __syncthreads();
    if (tid < NK) {
        float s2 = red[0][tid] + red[1][tid] + red[2][tid] + red[3][tid];
        ws[ACC_OFF + chunk * (BB * NF * NK) + (b * NF + f) * NK + tid] = s2;
    }
}

// ---------------------------------------------------------------------------
// K4: out[b,f,k] = sum_c accP[c] / (1e-4 + sum_q intgP[q])
// ---------------------------------------------------------------------------
__global__ void k_final(const float* __restrict__ ws, float* __restrict__ out) {
    int i = blockIdx.x * 256 + threadIdx.x;
    if (i >= BB * NF * NK) return;
    float a = 0.f;
    #pragma unroll
    for (int c = 0; c < CHUNKS; ++c) a += ws[ACC_OFF + c * (BB * NF * NK) + i];
    const int fk = i & (NF * NK - 1);
    float g = 1e-4f;
    #pragma unroll
    for (int q = 0; q < 4; ++q) g += ws[INTG_OFF + q * (NF * NK) + fk];
    out[i] = a / g;
}

extern "C" void kernel_launch(void* const* d_in, const int* in_sizes, int n_in,
                              void* d_out, int out_size, void* d_ws, size_t ws_size,
                              hipStream_t stream) {
    const float* field = (const float*)d_in[0];
    const float* quad  = (const float*)d_in[1];
    float* ws = (float*)d_ws;

    k_prep<<<640, 256, 0, stream>>>(quad,
        (const float*)d_in[2], (const float*)d_in[3],
        (const float*)d_in[4], (const float*)d_in[5],
        (const float*)d_in[6], (const float*)d_in[7],
        (const float*)d_in[8], ws);
    k_integral<<<NF * NK * 4, 256, 0, stream>>>(ws);
    k_main<<<BB * NF * CHUNKS, 256, 0, stream>>>(field, quad, ws);
    k_final<<<(BB * NF * NK + 255) / 256, 256, 0, stream>>>(ws, (float*)d_out);
}

// Round 7
// 237.891 us; speedup vs baseline: 2.8726x; 1.0096x over previous
//
#include <hip/hip_runtime.h>
#include <math.h>

// Problem constants (fixed by reference)
#define NF 8
#define NK 16
#define BB 32
#define YY 32
#define XX 32
#define PP 16
#define TT 8
#define YX (YY*XX)     // 1024
#define PT (PP*TT)     // 128
#define YXPT (YX*PT)   // 131072
#define CHUNKS 8
#define COLS_PER_BLOCK (YX/CHUNKS)        // 128
#define COLS_PER_WAVE  (COLS_PER_BLOCK/4) // 32
#define MAIN_ITERS     (COLS_PER_WAVE/2)  // 16 (2 columns per wave-iter)

// Workspace layout (float offsets)
#define WPT_OFF   0                          // [NF][NK][PT]         = 16384
#define WYX_OFF   (NF*NK*PT)                 // [NF][YX][NK]         = 131072
#define QMEAN_OFF (WYX_OFF + NF*YX*NK)       // [YXPT]               = 131072
#define ACC_OFF   (QMEAN_OFF + YXPT)         // [CHUNKS][BB*NF*NK]   = 32768
#define INTG_OFF  (ACC_OFF + CHUNKS*BB*NF*NK)// [4][NF*NK]           = 512

// ---------------------------------------------------------------------------
// K1: blocks 0..511  -> qmean (b-split 4 ways + LDS reduce)
//     blocks 512..639-> weight tables, one block per (f,k)
// ---------------------------------------------------------------------------
__global__ __launch_bounds__(256) void k_prep(const float* __restrict__ quad,
                       const float* __restrict__ mean_lat, const float* __restrict__ logstd_lat,
                       const float* __restrict__ mean_lon, const float* __restrict__ logstd_lon,
                       const float* __restrict__ mean_lev, const float* __restrict__ logstd_lev,
                       const float* __restrict__ logtau,
                       float* __restrict__ ws) {
    const int tid = threadIdx.x, bx = blockIdx.x;

    if (bx < 512) {
        __shared__ float4 sm[256];
        const int j4 = bx * 64 + (tid & 63);
        const int bg = tid >> 6;
        const float4* q4 = (const float4*)quad;
        float4 a = make_float4(0.f, 0.f, 0.f, 0.f);
        #pragma unroll
        for (int i = 0; i < 8; ++i) {
            float4 v = q4[(size_t)(bg * 8 + i) * (YXPT / 4) + j4];
            a.x += v.x; a.y += v.y; a.z += v.z; a.w += v.w;
        }
        sm[tid] = a;
        __syncthreads();
        if (tid < 64) {
            float4 r0 = sm[tid], r1 = sm[tid + 64], r2 = sm[tid + 128], r3 = sm[tid + 192];
            float4 r;
            r.x = (r0.x + r1.x + r2.x + r3.x) * (1.f / BB);
            r.y = (r0.y + r1.y + r2.y + r3.y) * (1.f / BB);
            r.z = (r0.z + r1.z + r2.z + r3.z) * (1.f / BB);
            r.w = (r0.w + r1.w + r2.w + r3.w) * (1.f / BB);
            ((float4*)(ws + QMEAN_OFF))[j4] = r;
        }
        return;
    }
    // weight tables: one block per fk, 128 active threads
    const int fk = bx - 512;
    if (tid >= 128) return;
    const int f = fk >> 4, k = fk & 15;
    const float mlat = mean_lat[fk], slat = expf(logstd_lat[fk]);
    const float mlon = mean_lon[fk], slon = expf(logstd_lon[fk]);
    const float mlev = mean_lev[fk], slev = expf(logstd_lev[fk]);
    const float tau  = expf(logtau[fk]) + 1e-4f;

    {   // wpt[fk][tid]:  p = tid>>3, t = tid&7  (coalesced store)
        const int p = tid >> 3, t = tid & 7;
        const float cp = -1.f + 2.f * (float)p / (PP - 1);
        const float zp = (cp - mlev) / slev;
        ws[WPT_OFF + fk * PT + tid] = expf(-0.5f * zp * zp) * expf(-(float)t / tau);
    }
    #pragma unroll
    for (int i = 0; i < 8; ++i) {   // wyx[f][yx][k]
        const int yx = i * 128 + tid;
        const int y = yx >> 5, x = yx & 31;
        const float cy = -1.f + 2.f * (float)y / (YY - 1);
        const float cx = -1.f + 2.f * (float)x / (XX - 1);
        const float zy = (cy - mlat) / slat;
        const float zx = (cx - mlon) / slon;
        ws[WYX_OFF + (f * YX + yx) * NK + k] = expf(-0.5f * zy * zy) * expf(-0.5f * zx * zx);
    }
}

// ---------------------------------------------------------------------------
// K2: quarter-partials of integral[f,k]; block = (fk, quarter), no atomics
// ---------------------------------------------------------------------------
__global__ __launch_bounds__(256) void k_integral(float* __restrict__ ws) {
    const int fk = blockIdx.x >> 2, qr = blockIdx.x & 3;
    const int tid = threadIdx.x;
    const int f = fk >> 4, k = fk & 15;
    const int yx = qr * 256 + tid;
    const float4* w4 = (const float4*)(ws + WPT_OFF + fk * PT);
    const float4* q4 = (const float4*)(ws + QMEAN_OFF + (size_t)yx * PT);
    float s = 0.f;
    #pragma unroll
    for (int j = 0; j < PT / 4; ++j) {
        float4 w = w4[j], q = q4[j];
        s += w.x * q.x + w.y * q.y + w.z * q.z + w.w * q.w;
    }
    float partial = ws[WYX_OFF + (f * YX + yx) * NK + k] * s;
    #pragma unroll
    for (int m = 32; m; m >>= 1) partial += __shfl_xor(partial, m);
    __shared__ float red[4];
    if ((tid & 63) == 0) red[tid >> 6] = partial;
    __syncthreads();
    if (tid == 0)
        ws[INTG_OFF + qr * (NF * NK) + fk] = red[0] + red[1] + red[2] + red[3];
}

// ---------------------------------------------------------------------------
// K3: main contraction. Block = (b, f, chunk of 128 cols); 4 waves.
// wyx slice staged in LDS (8 KB). Distance-3 software pipeline with
// #pragma unroll 1: exactly 6 outstanding 16B loads/lane, bounded registers.
// launch_bounds (256,3): 170-VGPR cap -- (256,4)'s 128 cap caused the R5
// scratch-spill disaster (614 MB spill writes). Plain loads only (gfx950
// nontemporal bypasses L2 merging -> 8x over-fetch, R4/R5).
// Each block writes its own partial slot (no atomics, no zero-init needed).
// ---------------------------------------------------------------------------
__global__ __launch_bounds__(256, 3) void k_main(const float* __restrict__ field,
                                                 const float* __restrict__ quad,
                                                 float* __restrict__ ws) {
    const int bx = blockIdx.x;
    const int f = bx & 7, chunk = (bx >> 3) & 7, b = bx >> 6;
    const int tid = threadIdx.x;
    const int wave = tid >> 6, L = tid & 63;
    const int half = L >> 5, qg = L & 31;

    __shared__ float sw[COLS_PER_BLOCK * NK]; // 8 KB: [col][k]
    {
        const float4* src = (const float4*)(ws + WYX_OFF + (size_t)(f * YX + chunk * COLS_PER_BLOCK) * NK);
        float4* dst = (float4*)sw;
        dst[tid] = src[tid];
        dst[tid + 256] = src[tid + 256];
    }

    float4 wf[NK];
    #pragma unroll
    for (int k = 0; k < NK; ++k)
        wf[k] = *(const float4*)(ws + WPT_OFF + (f * NK + k) * PT + 4 * qg);

    float acc[NK];
    #pragma unroll
    for (int k = 0; k < NK; ++k) acc[k] = 0.f;

    const int colBase = chunk * COLS_PER_BLOCK + wave * COLS_PER_WAVE;
    const float4* fp = (const float4*)(field + (size_t)(b * NF + f) * YXPT + (size_t)colBase * PT + 4 * L);
    const float4* qp = (const float4*)(quad + (size_t)b * YXPT + (size_t)colBase * PT + 4 * L);
    const int STEP = (2 * PT) / 4;   // 2 columns per iter

    __syncthreads();
    const float* swc = sw + (wave * COLS_PER_WAVE + half) * NK;

    // distance-3 pipeline preamble (6 outstanding 16B loads/lane)
    float4 fa = fp[0];
    float4 qa = qp[0];
    float4 fb = fp[STEP];
    float4 qb = qp[STEP];
    float4 fc = fp[2 * STEP];
    float4 qc = qp[2 * STEP];

    #pragma unroll 1
    for (int s = 0; s < MAIN_ITERS; ++s) {
        // prefetch s+3 (clamped, branchless; redundant tail loads are L2 hits)
        const int sn = (s + 3 < MAIN_ITERS) ? (s + 3) : 0;
        float4 fd = fp[sn * STEP];
        float4 qd = qp[sn * STEP];

        float4 ga;
        ga.x = fa.x * qa.x; ga.y = fa.y * qa.y; ga.z = fa.z * qa.z; ga.w = fa.w * qa.w;

        const float4* wvp = (const float4*)(swc + s * 2 * NK);
        #pragma unroll
        for (int j = 0; j < 4; ++j) {
            float4 w = wvp[j];
            {
                const int k = 4 * j;
                float d = ga.x * wf[k].x;
                d = fmaf(ga.y, wf[k].y, d);
                d = fmaf(ga.z, wf[k].z, d);
                d = fmaf(ga.w, wf[k].w, d);
                acc[k] = fmaf(w.x, d, acc[k]);
            }
            {
                const int k = 4 * j + 1;
                float d = ga.x * wf[k].x;
                d = fmaf(ga.y, wf[k].y, d);
                d = fmaf(ga.z, wf[k].z, d);
                d = fmaf(ga.w, wf[k].w, d);
                acc[k] = fmaf(w.y, d, acc[k]);
            }
            {
                const int k = 4 * j + 2;
                float d = ga.x * wf[k].x;
                d = fmaf(ga.y, wf[k].y, d);
                d = fmaf(ga.z, wf[k].z, d);
                d = fmaf(ga.w, wf[k].w, d);
                acc[k] = fmaf(w.z, d, acc[k]);
            }
            {
                const int k = 4 * j + 3;
                float d = ga.x * wf[k].x;
                d = fmaf(ga.y, wf[k].y, d);
                d = fmaf(ga.z, wf[k].z, d);
                d = fmaf(ga.w, wf[k].w, d);
                acc[k] = fmaf(w.w, d, acc[k]);
            }
        }
        fa = fb; qa = qb;
        fb = fc; qb = qc;
        fc = fd; qc = qd;
    }

    // wave butterfly -> cross-wave LDS -> one plain store per k (chunk slot)
    __shared__ float red[4][NK];
    #pragma unroll
    for (int k = 0; k < NK; ++k) {
        float v = acc[k];
        v += __shfl_xor(v, 32); v += __shfl_xor(v, 16); v += __shfl_xor(v, 8);
        v += __shfl_xor(v, 4);  v += __shfl_xor(v, 2);  v += __shfl_xor(v, 1);
        if (L == 0) red[wave][k] = v;
    }
    __syncthreads();
    if (tid < NK) {
        float s2 = red[0][tid] + red[1][tid] + red[2][tid] + red[3][tid];
        ws[ACC_OFF + chunk * (BB * NF * NK) + (b * NF + f) * NK + tid] = s2;
    }
}

// ---------------------------------------------------------------------------
// K4: out[b,f,k] = sum_c accP[c] / (1e-4 + sum_q intgP[q])
// ---------------------------------------------------------------------------
__global__ void k_final(const float* __restrict__ ws, float* __restrict__ out) {
    int i = blockIdx.x * 256 + threadIdx.x;
    if (i >= BB * NF * NK) return;
    float a = 0.f;
    #pragma unroll
    for (int c = 0; c < CHUNKS; ++c) a += ws[ACC_OFF + c * (BB * NF * NK) + i];
    const int fk = i & (NF * NK - 1);
    float g = 1e-4f;
    #pragma unroll
    for (int q = 0; q < 4; ++q) g += ws[INTG_OFF + q * (NF * NK) + fk];
    out[i] = a / g;
}

extern "C" void kernel_launch(void* const* d_in, const int* in_sizes, int n_in,
                              void* d_out, int out_size, void* d_ws, size_t ws_size,
                              hipStream_t stream) {
    const float* field = (const float*)d_in[0];
    const float* quad  = (const float*)d_in[1];
    float* ws = (float*)d_ws;

    k_prep<<<640, 256, 0, stream>>>(quad,
        (const float*)d_in[2], (const float*)d_in[3],
        (const float*)d_in[4], (const float*)d_in[5],
        (const float*)d_in[6], (const float*)d_in[7],
        (const float*)d_in[8], ws);
    k_integral<<<NF * NK * 4, 256, 0, stream>>>(ws);
    k_main<<<BB * NF * CHUNKS, 256, 0, stream>>>(field, quad, ws);
    k_final<<<(BB * NF * NK + 255) / 256, 256, 0, stream>>>(ws, (float*)d_out);
}